// Round 4
// baseline (227.543 us; speedup 1.0000x reference)
//
#include <hip/hip_runtime.h>

typedef unsigned short u16;
typedef unsigned int u32;
typedef __attribute__((ext_vector_type(8))) short short8;
typedef __attribute__((ext_vector_type(4))) float float4v;

static inline int cdiv(int a, int b) { return (a + b - 1) / b; }

__device__ __forceinline__ u16 f2bf(float f) {
    u32 u = __float_as_uint(f);
    u = (u + 0x7fffu + ((u >> 16) & 1u)) >> 16;
    return (u16)u;
}
__device__ __forceinline__ float bf2f(u16 s) {
    return __uint_as_float(((u32)s) << 16);
}

// W (K rows, COUT cols) fp32 -> transposed bf16 hi/lo (COUT, K)
__global__ __launch_bounds__(256) void wsplit(
    const float* __restrict__ W, u16* __restrict__ th, u16* __restrict__ tl,
    int K, int COUT)
{
    int e = blockIdx.x * 256 + threadIdx.x;
    if (e >= K * COUT) return;
    int kk = e / COUT, co = e % COUT;
    float w = W[e];
    u16 h = f2bf(w);
    u16 l = f2bf(w - bf2f(h));
    th[(size_t)co * K + kk] = h;
    tl[(size_t)co * K + kk] = l;
}

// ------ Layer 1: C_in=1 -> 16, k-split x4 in-block; interleaved h/l out ------
__global__ __launch_bounds__(256) void conv_l1(
    const float* __restrict__ feats, const int* __restrict__ nmap,
    const float* __restrict__ W, u16* __restrict__ o, int N)
{
    __shared__ float4 w4[27 * 4];
    __shared__ float part[4][64][17];
    for (int i = threadIdx.x; i < 27 * 4; i += 256)
        w4[i] = reinterpret_cast<const float4*>(W)[i];
    __syncthreads();

    const int tx = threadIdx.x & 63;
    const int tz = threadIdx.x >> 6;
    const int row = blockIdx.x * 64 + tx;

    float acc[16];
#pragma unroll
    for (int j = 0; j < 16; ++j) acc[j] = 0.f;

#pragma unroll
    for (int s = 0; s < 7; ++s) {
        int k = tz * 7 + s;
        if (k < 27) {
            int idx = (row < N) ? nmap[(size_t)k * N + row] : -1;
            float v = (idx >= 0) ? feats[idx] : 0.f;
#pragma unroll
            for (int cq = 0; cq < 4; ++cq) {
                float4 w = w4[k * 4 + cq];
                acc[cq * 4 + 0] = fmaf(v, w.x, acc[cq * 4 + 0]);
                acc[cq * 4 + 1] = fmaf(v, w.y, acc[cq * 4 + 1]);
                acc[cq * 4 + 2] = fmaf(v, w.z, acc[cq * 4 + 2]);
                acc[cq * 4 + 3] = fmaf(v, w.w, acc[cq * 4 + 3]);
            }
        }
    }
#pragma unroll
    for (int c = 0; c < 16; ++c) part[tz][tx][c] = acc[c];
    __syncthreads();

    const int r = threadIdx.x & 63;
    const int cs = (threadIdx.x >> 6) * 4;
    const int orow = blockIdx.x * 64 + r;
    if (orow >= N) return;
    float ov[4];
#pragma unroll
    for (int j = 0; j < 4; ++j) {
        float a = part[0][r][cs + j];
#pragma unroll
        for (int p = 1; p < 4; ++p) a += part[p][r][cs + j];
        ov[j] = a;
    }
    u32 h01 = (u32)f2bf(ov[0]) | ((u32)f2bf(ov[1]) << 16);
    u32 h23 = (u32)f2bf(ov[2]) | ((u32)f2bf(ov[3]) << 16);
    float l0 = ov[0] - bf2f(f2bf(ov[0])), l1 = ov[1] - bf2f(f2bf(ov[1]));
    float l2 = ov[2] - bf2f(f2bf(ov[2])), l3 = ov[3] - bf2f(f2bf(ov[3]));
    u32 g01 = (u32)f2bf(l0) | ((u32)f2bf(l1) << 16);
    u32 g23 = (u32)f2bf(l2) | ((u32)f2bf(l3) << 16);
    // interleaved row: [16 h][16 l], stride 32
    *reinterpret_cast<uint2*>(o + (size_t)orow * 32 + cs) = make_uint2(h01, h23);
    *reinterpret_cast<uint2*>(o + (size_t)orow * 32 + 16 + cs) = make_uint2(g01, g23);
}

// ------ Pipelined direct-fragment MFMA gathered GEMM (no LDS) ------
// x interleaved: [row][2*CIN] (h then l). Wt: [co][K] h and l arrays.
// idx prefetch distance 3 (4 bufs), fragment prefetch distance 1 (2 bufs),
// K-loop fully unrolled so all buffer indices are compile-time.
template<int CIN, int COUT, int BM, int BN, int WAVES_M, int WAVES_N,
         int KSPLIT, bool BFOUT>
__global__ __launch_bounds__(256) void conv_direct(
    const u16* __restrict__ x, const int* __restrict__ nmap,
    const u16* __restrict__ wth, const u16* __restrict__ wtl,
    float* __restrict__ outf, u16* __restrict__ o, int N)
{
    constexpr int K = 27 * CIN;
    constexpr int KSTEPS = (K + 31) / 32;
    static_assert(KSTEPS % KSPLIT == 0, "ksplit divides ksteps");
    constexpr int KPER = KSTEPS / KSPLIT;
    constexpr int WM = BM / WAVES_M, WN = BN / WAVES_N;
    static_assert(WAVES_M * WAVES_N == 4, "4 waves");
    constexpr int FM = WM / 16, FN = WN / 16;

    const int lane = threadIdx.x & 63;
    const int wave = threadIdx.x >> 6;
    const int wm = wave / WAVES_N, wn = wave % WAVES_N;
    const int fr = lane & 15;
    const int kc = (lane >> 4) * 8;
    const int row0 = blockIdx.x * BM + wm * WM;
    const int co0 = blockIdx.y * BN + wn * WN;
    const int kz = blockIdx.z;
    const int ks0 = kz * KPER;

    float4v acc[FM][FN];
#pragma unroll
    for (int i = 0; i < FM; ++i)
#pragma unroll
        for (int j = 0; j < FN; ++j) acc[i][j] = (float4v){0.f, 0.f, 0.f, 0.f};

    int idxb[4][FM];
    short8 ahb[2][FM], alb[2][FM], bhb[2][FN], blb[2][FN];

    auto load_idx = [&](int s, int slot) {
        int kk = (ks0 + s) * 32 + kc;
        int koff = kk / CIN;
#pragma unroll
        for (int i = 0; i < FM; ++i) {
            int r = row0 + i * 16 + fr;
            idxb[slot][i] = (kk < K && r < N) ? nmap[(size_t)koff * N + r] : -1;
        }
    };
    auto load_frag = [&](int s, int islot, int p) {
        int kk = (ks0 + s) * 32 + kc;
        int cpos = kk & (CIN - 1);
#pragma unroll
        for (int i = 0; i < FM; ++i) {
            int idx = idxb[islot][i];
            short8 h = (short8){0,0,0,0,0,0,0,0}, l = (short8){0,0,0,0,0,0,0,0};
            if (idx >= 0) {
                const u16* base = x + (size_t)idx * (2 * CIN) + cpos;
                h = *reinterpret_cast<const short8*>(base);
                l = *reinterpret_cast<const short8*>(base + CIN);
            }
            ahb[p][i] = h; alb[p][i] = l;
        }
#pragma unroll
        for (int j = 0; j < FN; ++j) {
            short8 h = (short8){0,0,0,0,0,0,0,0}, l = (short8){0,0,0,0,0,0,0,0};
            if (kk < K) {
                size_t b = (size_t)(co0 + j * 16 + fr) * K + kk;
                h = *reinterpret_cast<const short8*>(wth + b);
                l = *reinterpret_cast<const short8*>(wtl + b);
            }
            bhb[p][j] = h; blb[p][j] = l;
        }
    };
    auto do_mfma = [&](int p) {
#pragma unroll
        for (int i = 0; i < FM; ++i)
#pragma unroll
            for (int j = 0; j < FN; ++j) {
                acc[i][j] = __builtin_amdgcn_mfma_f32_16x16x32_bf16(ahb[p][i], bhb[p][j], acc[i][j], 0, 0, 0);
                acc[i][j] = __builtin_amdgcn_mfma_f32_16x16x32_bf16(ahb[p][i], blb[p][j], acc[i][j], 0, 0, 0);
                acc[i][j] = __builtin_amdgcn_mfma_f32_16x16x32_bf16(alb[p][i], bhb[p][j], acc[i][j], 0, 0, 0);
            }
    };

    load_idx(0, 0);
    if (KPER > 1) load_idx(1, 1);
    if (KPER > 2) load_idx(2, 2);
    load_frag(0, 0, 0);
#pragma unroll
    for (int s = 0; s < KPER; ++s) {
        if (s + 1 < KPER) load_frag(s + 1, (s + 1) & 3, (s + 1) & 1);
        if (s + 3 < KPER) load_idx(s + 3, (s + 3) & 3);
        do_mfma(s & 1);
    }

    // D layout: row=(lane>>4)*4+q, col=lane&15 (m89)
    const int orow0 = row0 + (lane >> 4) * 4;
    const int ocol0 = co0 + fr;
#pragma unroll
    for (int i = 0; i < FM; ++i)
#pragma unroll
        for (int j = 0; j < FN; ++j)
#pragma unroll
            for (int q = 0; q < 4; ++q) {
                int r = orow0 + i * 16 + q;
                int c = ocol0 + j * 16;
                if (r < N) {
                    float v = acc[i][j][q];
                    if constexpr (BFOUT) {
                        u16 h = f2bf(v);
                        o[(size_t)r * (2 * COUT) + c] = h;
                        o[(size_t)r * (2 * COUT) + COUT + c] = f2bf(v - bf2f(h));
                    } else {
                        outf[(size_t)kz * N * COUT + (size_t)r * COUT + c] = v;
                    }
                }
            }
}

// ------ deterministic fixed-order K-split reductions ------
__global__ __launch_bounds__(256) void reduce_f32(
    const float* __restrict__ p, float* __restrict__ out, int m4, int S)
{
    int i = blockIdx.x * 256 + threadIdx.x;
    if (i >= m4) return;
    const float4* p4 = reinterpret_cast<const float4*>(p);
    float4 a = p4[i];
    for (int s = 1; s < S; ++s) {
        float4 v = p4[(size_t)s * m4 + i];
        a.x += v.x; a.y += v.y; a.z += v.z; a.w += v.w;
    }
    reinterpret_cast<float4*>(out)[i] = a;
}
template<int C>
__global__ __launch_bounds__(256) void reduce_bf(
    const float* __restrict__ p, u16* __restrict__ o, int m, int S)
{
    int i = blockIdx.x * 256 + threadIdx.x;
    if (i >= m) return;
    float a = p[i];
    for (int s = 1; s < S; ++s) a += p[(size_t)s * m + i];
    int r = i / C, c = i % C;
    u16 h = f2bf(a);
    o[(size_t)r * (2 * C) + c] = h;
    o[(size_t)r * (2 * C) + C + c] = f2bf(a - bf2f(h));
}

extern "C" void kernel_launch(void* const* d_in, const int* in_sizes, int n_in,
                              void* d_out, int out_size, void* d_ws, size_t ws_size,
                              hipStream_t stream)
{
    const float* feats = (const float*)d_in[0];
    const float* W1 = (const float*)d_in[1];
    const int*   nm1 = (const int*)d_in[2];
    const float* W2 = (const float*)d_in[3];
    const int*   nm2 = (const int*)d_in[4];
    const float* W3 = (const float*)d_in[5];
    const int*   nm3 = (const int*)d_in[6];
    const float* W4 = (const float*)d_in[7];
    const int*   nm4 = (const int*)d_in[8];
    const float* W5 = (const float*)d_in[9];
    const int*   nm5 = (const int*)d_in[10];

    const int M1 = in_sizes[2] / 27;
    const int M2 = in_sizes[4] / 27;
    const int M3 = in_sizes[6] / 27;
    const int M4 = in_sizes[8] / 27;
    const int M5 = in_sizes[10] / 27;

    u16* x1 = (u16*)d_ws;                        // M1 x 32
    u16* x2 = x1 + (size_t)M1 * 32;              // M2 x 64
    u16* x3 = x2 + (size_t)M2 * 64;              // M3 x 128
    u16* x4 = x3 + (size_t)M3 * 128;             // M4 x 256
    u16* wt2h = x4 + (size_t)M4 * 256;
    u16* wt2l = wt2h + 432 * 32;
    u16* wt3h = wt2l + 432 * 32;
    u16* wt3l = wt3h + 864 * 64;
    u16* wt4h = wt3l + 864 * 64;
    u16* wt4l = wt4h + 1728 * 128;
    u16* wt5h = wt4l + 1728 * 128;
    u16* wt5l = wt5h + (size_t)3456 * 512;
    u16* uend = wt5l + (size_t)3456 * 512;
    float* p4 = (float*)(((uintptr_t)uend + 15) & ~(uintptr_t)15);
    float* p5 = p4 + (size_t)2 * M4 * 128;

    wsplit<<<cdiv(432 * 32, 256), 256, 0, stream>>>(W2, wt2h, wt2l, 432, 32);
    wsplit<<<cdiv(864 * 64, 256), 256, 0, stream>>>(W3, wt3h, wt3l, 864, 64);
    wsplit<<<cdiv(1728 * 128, 256), 256, 0, stream>>>(W4, wt4h, wt4l, 1728, 128);
    wsplit<<<cdiv(3456 * 512, 256), 256, 0, stream>>>(W5, wt5h, wt5l, 3456, 512);

    conv_l1<<<cdiv(M1, 64), 256, 0, stream>>>(feats, nm1, W1, x1, M1);

    // L2: 16 -> 32, block 256x32 (waves 4x1 of 64x32), KPER=14
    conv_direct<16, 32, 256, 32, 4, 1, 1, true>
        <<<dim3(cdiv(M2, 256), 1, 1), 256, 0, stream>>>(
            x1, nm2, wt2h, wt2l, nullptr, x2, M2);
    // L3: 32 -> 64, block 128x64 (waves 2x2 of 64x32), KPER=27
    conv_direct<32, 64, 128, 64, 2, 2, 1, true>
        <<<dim3(cdiv(M3, 128), 1, 1), 256, 0, stream>>>(
            x2, nm3, wt3h, wt3l, nullptr, x3, M3);
    // L4: 64 -> 128, block 64x128 (waves 1x4 of 64x32), K-split 2, KPER=27
    conv_direct<64, 128, 64, 128, 1, 4, 2, false>
        <<<dim3(cdiv(M4, 64), 1, 2), 256, 0, stream>>>(
            x3, nm4, wt4h, wt4l, p4, nullptr, M4);
    reduce_bf<128><<<cdiv(M4 * 128, 256), 256, 0, stream>>>(p4, x4, M4 * 128, 2);
    // L5: 128 -> 512, block 64x128 (waves 1x4 of 64x32), K-split 4, KPER=27
    conv_direct<128, 512, 64, 128, 1, 4, 4, false>
        <<<dim3(cdiv(M5, 64), 4, 4), 256, 0, stream>>>(
            x4, nm5, wt5h, wt5l, p5, nullptr, M5);
    reduce_f32<<<cdiv(M5 * 512 / 4, 256), 256, 0, stream>>>(p5, (float*)d_out, M5 * 512 / 4, 4);
}

// Round 5
// 216.121 us; speedup vs baseline: 1.0528x; 1.0528x over previous
//
#include <hip/hip_runtime.h>

typedef unsigned short u16;
typedef unsigned int u32;
typedef __attribute__((ext_vector_type(8))) short short8;
typedef __attribute__((ext_vector_type(4))) float float4v;

static inline int cdiv(int a, int b) { return (a + b - 1) / b; }

__device__ __forceinline__ u16 f2bf(float f) {
    u32 u = __float_as_uint(f);
    u = (u + 0x7fffu + ((u >> 16) & 1u)) >> 16;
    return (u16)u;
}
__device__ __forceinline__ float bf2f(u16 s) {
    return __uint_as_float(((u32)s) << 16);
}

typedef __attribute__((address_space(3))) u16 lds_u16;
typedef __attribute__((address_space(1))) const u16 glb_u16;
__device__ __forceinline__ void gl_lds16(const u16* g, u16* l) {
    __builtin_amdgcn_global_load_lds((glb_u16*)g, (lds_u16*)l, 16, 0, 0);
}

__global__ void zinit(u16* zp) { zp[threadIdx.x] = 0; }

// W (K rows, COUT cols) fp32 -> transposed bf16 hi/lo (COUT, K)
__global__ __launch_bounds__(256) void wsplit(
    const float* __restrict__ W, u16* __restrict__ th, u16* __restrict__ tl,
    int K, int COUT)
{
    int e = blockIdx.x * 256 + threadIdx.x;
    if (e >= K * COUT) return;
    int kk = e / COUT, co = e % COUT;
    float w = W[e];
    u16 h = f2bf(w);
    u16 l = f2bf(w - bf2f(h));
    th[(size_t)co * K + kk] = h;
    tl[(size_t)co * K + kk] = l;
}

// ------ Layer 1: C_in=1 -> 16, k-split x4 in-block; interleaved h/l out ------
__global__ __launch_bounds__(256) void conv_l1(
    const float* __restrict__ feats, const int* __restrict__ nmap,
    const float* __restrict__ W, u16* __restrict__ o, int N)
{
    __shared__ float4 w4[27 * 4];
    __shared__ float part[4][64][17];
    for (int i = threadIdx.x; i < 27 * 4; i += 256)
        w4[i] = reinterpret_cast<const float4*>(W)[i];
    __syncthreads();

    const int tx = threadIdx.x & 63;
    const int tz = threadIdx.x >> 6;
    const int row = blockIdx.x * 64 + tx;

    float acc[16];
#pragma unroll
    for (int j = 0; j < 16; ++j) acc[j] = 0.f;

#pragma unroll
    for (int s = 0; s < 7; ++s) {
        int k = tz * 7 + s;
        if (k < 27) {
            int idx = (row < N) ? nmap[(size_t)k * N + row] : -1;
            float v = (idx >= 0) ? feats[idx] : 0.f;
#pragma unroll
            for (int cq = 0; cq < 4; ++cq) {
                float4 w = w4[k * 4 + cq];
                acc[cq * 4 + 0] = fmaf(v, w.x, acc[cq * 4 + 0]);
                acc[cq * 4 + 1] = fmaf(v, w.y, acc[cq * 4 + 1]);
                acc[cq * 4 + 2] = fmaf(v, w.z, acc[cq * 4 + 2]);
                acc[cq * 4 + 3] = fmaf(v, w.w, acc[cq * 4 + 3]);
            }
        }
    }
#pragma unroll
    for (int c = 0; c < 16; ++c) part[tz][tx][c] = acc[c];
    __syncthreads();

    const int r = threadIdx.x & 63;
    const int cs = (threadIdx.x >> 6) * 4;
    const int orow = blockIdx.x * 64 + r;
    if (orow >= N) return;
    float ov[4];
#pragma unroll
    for (int j = 0; j < 4; ++j) {
        float a = part[0][r][cs + j];
#pragma unroll
        for (int p = 1; p < 4; ++p) a += part[p][r][cs + j];
        ov[j] = a;
    }
    u32 h01 = (u32)f2bf(ov[0]) | ((u32)f2bf(ov[1]) << 16);
    u32 h23 = (u32)f2bf(ov[2]) | ((u32)f2bf(ov[3]) << 16);
    float l0 = ov[0] - bf2f(f2bf(ov[0])), l1 = ov[1] - bf2f(f2bf(ov[1]));
    float l2 = ov[2] - bf2f(f2bf(ov[2])), l3 = ov[3] - bf2f(f2bf(ov[3]));
    u32 g01 = (u32)f2bf(l0) | ((u32)f2bf(l1) << 16);
    u32 g23 = (u32)f2bf(l2) | ((u32)f2bf(l3) << 16);
    *reinterpret_cast<uint2*>(o + (size_t)orow * 32 + cs) = make_uint2(h01, h23);
    *reinterpret_cast<uint2*>(o + (size_t)orow * 32 + 16 + cs) = make_uint2(g01, g23);
}

// ------ LDS-staged MFMA gathered GEMM (global_load_lds gather pipeline) ------
// A gathered into LDS via async DMA (per-lane global addr, linear LDS dest),
// double-buffered, chunk-swizzled (c ^ ((row>>1)&3)) for 2-way bank reads.
// B = Wt[co][K] hi/lo direct-to-register (L1-resident), 1-step prefetch.
// x interleaved: [row][2*CIN] (h then l).
template<int CIN, int COUT, int BN, int WAVES_M, int WAVES_N, int KSPLIT, bool BFOUT>
__global__ __launch_bounds__(256) void conv_lds(
    const u16* __restrict__ x, const int* __restrict__ nmap,
    const u16* __restrict__ wth, const u16* __restrict__ wtl,
    const u16* __restrict__ zp,
    float* __restrict__ outf, u16* __restrict__ o, int N)
{
    constexpr int BM = 128;
    constexpr int K = 27 * CIN;
    constexpr int KSTEPS = (K + 31) / 32;
    static_assert(KSTEPS % KSPLIT == 0, "ksplit divides ksteps");
    constexpr int KPER = KSTEPS / KSPLIT;
    constexpr int WM = BM / WAVES_M, WN = BN / WAVES_N;
    static_assert(WAVES_M * WAVES_N == 4, "4 waves");
    constexpr int FM = WM / 16, FN = WN / 16;

    // [buf][h/l][BM*32 u16] ; per buffer-half 8 KB = 8 chunks of 1 KB
    __shared__ __align__(16) u16 Asg[2][2][BM * 32];

    const int lane = threadIdx.x & 63;
    const int wave = threadIdx.x >> 6;
    const int wm = wave / WAVES_N, wn = wave % WAVES_N;
    const int fr = lane & 15;
    const int q8 = (lane >> 4) * 8;
    const int row0 = blockIdx.x * BM;
    const int co0 = blockIdx.y * BN;
    const int kz = blockIdx.z;
    const int ks0 = kz * KPER;

    // staging lane map: instr t covers chunk (wave + t*4) = rows [ch*16, ch*16+16)
    int rowS[2], clog[2];
#pragma unroll
    for (int t = 0; t < 2; ++t) {
        int ch = wave + t * 4;
        rowS[t] = ch * 16 + (lane >> 2);
        clog[t] = (lane & 3) ^ ((rowS[t] >> 1) & 3);
    }
    // fragment read offsets (u16 elems within one [BM*32] plane)
    int aoff[FM];
#pragma unroll
    for (int i = 0; i < FM; ++i) {
        int rt = wm * WM + i * 16 + fr;
        aoff[i] = rt * 32 + (((lane >> 4) ^ ((rt >> 1) & 3)) * 8);
    }
    const u16* bph[FN];
    const u16* bpl[FN];
#pragma unroll
    for (int j = 0; j < FN; ++j) {
        bph[j] = wth + (size_t)(co0 + wn * WN + j * 16 + fr) * K;
        bpl[j] = wtl + (size_t)(co0 + wn * WN + j * 16 + fr) * K;
    }

    float4v acc[FM][FN];
#pragma unroll
    for (int i = 0; i < FM; ++i)
#pragma unroll
        for (int j = 0; j < FN; ++j) acc[i][j] = (float4v){0.f, 0.f, 0.f, 0.f};

    int idxq[2][2];
    short8 bh[2][FN], bl[2][FN];
    const short8 zero8 = (short8){0, 0, 0, 0, 0, 0, 0, 0};

    auto load_idx = [&](int s, int p) {
#pragma unroll
        for (int t = 0; t < 2; ++t) {
            int kk = (ks0 + s) * 32 + clog[t] * 8;
            int koff = kk / CIN;
            if (koff > 26) koff = 26;
            int r = row0 + rowS[t];
            int rc = (r < N) ? r : (N - 1);
            int v = nmap[(size_t)koff * N + rc];
            idxq[p][t] = (r < N) ? v : -1;
        }
    };
    auto stage = [&](int s, int p, int b) {
#pragma unroll
        for (int t = 0; t < 2; ++t) {
            int kk = (ks0 + s) * 32 + clog[t] * 8;
            int cpos = kk & (CIN - 1);
            int idx = idxq[p][t];
            const u16* srcH = (idx >= 0) ? (x + (size_t)idx * (2 * CIN) + cpos) : zp;
            const u16* srcL = (idx >= 0) ? (srcH + CIN) : zp;
            u16* dstH = &Asg[b][0][(wave + t * 4) * 512];
            u16* dstL = &Asg[b][1][(wave + t * 4) * 512];
            gl_lds16(srcH, dstH);
            gl_lds16(srcL, dstL);
        }
    };
    auto loadB = [&](int s, int p) {
        int kkb = (ks0 + s) * 32 + q8;
        bool ok = (kkb < K);
#pragma unroll
        for (int j = 0; j < FN; ++j) {
            bh[p][j] = ok ? *reinterpret_cast<const short8*>(bph[j] + kkb) : zero8;
            bl[p][j] = ok ? *reinterpret_cast<const short8*>(bpl[j] + kkb) : zero8;
        }
    };
    auto mm = [&](int b, int p) {
        short8 ah[FM], al[FM];
#pragma unroll
        for (int i = 0; i < FM; ++i) {
            ah[i] = *reinterpret_cast<const short8*>(&Asg[b][0][aoff[i]]);
            al[i] = *reinterpret_cast<const short8*>(&Asg[b][1][aoff[i]]);
        }
#pragma unroll
        for (int i = 0; i < FM; ++i)
#pragma unroll
            for (int j = 0; j < FN; ++j) {
                acc[i][j] = __builtin_amdgcn_mfma_f32_16x16x32_bf16(ah[i], bh[p][j], acc[i][j], 0, 0, 0);
                acc[i][j] = __builtin_amdgcn_mfma_f32_16x16x32_bf16(ah[i], bl[p][j], acc[i][j], 0, 0, 0);
                acc[i][j] = __builtin_amdgcn_mfma_f32_16x16x32_bf16(al[i], bh[p][j], acc[i][j], 0, 0, 0);
            }
    };

    load_idx(0, 0);
    load_idx(1, 1);
    loadB(0, 0);
    stage(0, 0, 0);
    __syncthreads();

#pragma unroll
    for (int s = 0; s < KPER; ++s) {
        if (s + 1 < KPER) stage(s + 1, (s + 1) & 1, (s + 1) & 1);
        if (s + 2 < KPER) load_idx(s + 2, s & 1);
        if (s + 1 < KPER) loadB(s + 1, (s + 1) & 1);
        mm(s & 1, s & 1);
        __syncthreads();
    }

    // D layout: row=(lane>>4)*4+q, col=lane&15 (m89)
    const int orow0 = row0 + wm * WM + (lane >> 4) * 4;
    const int ocol0 = co0 + wn * WN + fr;
#pragma unroll
    for (int i = 0; i < FM; ++i)
#pragma unroll
        for (int j = 0; j < FN; ++j)
#pragma unroll
            for (int qq = 0; qq < 4; ++qq) {
                int r = orow0 + i * 16 + qq;
                int c = ocol0 + j * 16;
                if (r < N) {
                    float v = acc[i][j][qq];
                    if constexpr (BFOUT) {
                        u16 h = f2bf(v);
                        o[(size_t)r * (2 * COUT) + c] = h;
                        o[(size_t)r * (2 * COUT) + COUT + c] = f2bf(v - bf2f(h));
                    } else {
                        outf[(size_t)kz * N * COUT + (size_t)r * COUT + c] = v;
                    }
                }
            }
}

// ------ deterministic fixed-order K-split reductions ------
__global__ __launch_bounds__(256) void reduce_f32(
    const float* __restrict__ p, float* __restrict__ out, int m4, int S)
{
    int i = blockIdx.x * 256 + threadIdx.x;
    if (i >= m4) return;
    const float4* p4 = reinterpret_cast<const float4*>(p);
    float4 a = p4[i];
    for (int s = 1; s < S; ++s) {
        float4 v = p4[(size_t)s * m4 + i];
        a.x += v.x; a.y += v.y; a.z += v.z; a.w += v.w;
    }
    reinterpret_cast<float4*>(out)[i] = a;
}
template<int C>
__global__ __launch_bounds__(256) void reduce_bf(
    const float* __restrict__ p, u16* __restrict__ o, int m, int S)
{
    int i = blockIdx.x * 256 + threadIdx.x;
    if (i >= m) return;
    float a = p[i];
    for (int s = 1; s < S; ++s) a += p[(size_t)s * m + i];
    int r = i / C, c = i % C;
    u16 h = f2bf(a);
    o[(size_t)r * (2 * C) + c] = h;
    o[(size_t)r * (2 * C) + C + c] = f2bf(a - bf2f(h));
}

extern "C" void kernel_launch(void* const* d_in, const int* in_sizes, int n_in,
                              void* d_out, int out_size, void* d_ws, size_t ws_size,
                              hipStream_t stream)
{
    const float* feats = (const float*)d_in[0];
    const float* W1 = (const float*)d_in[1];
    const int*   nm1 = (const int*)d_in[2];
    const float* W2 = (const float*)d_in[3];
    const int*   nm2 = (const int*)d_in[4];
    const float* W3 = (const float*)d_in[5];
    const int*   nm3 = (const int*)d_in[6];
    const float* W4 = (const float*)d_in[7];
    const int*   nm4 = (const int*)d_in[8];
    const float* W5 = (const float*)d_in[9];
    const int*   nm5 = (const int*)d_in[10];

    const int M1 = in_sizes[2] / 27;
    const int M2 = in_sizes[4] / 27;
    const int M3 = in_sizes[6] / 27;
    const int M4 = in_sizes[8] / 27;
    const int M5 = in_sizes[10] / 27;

    u16* zp = (u16*)d_ws;                        // 128 u16 zero page
    u16* x1 = zp + 128;                          // M1 x 32
    u16* x2 = x1 + (size_t)M1 * 32;              // M2 x 64
    u16* x3 = x2 + (size_t)M2 * 64;              // M3 x 128
    u16* x4 = x3 + (size_t)M3 * 128;             // M4 x 256
    u16* wt2h = x4 + (size_t)M4 * 256;
    u16* wt2l = wt2h + 432 * 32;
    u16* wt3h = wt2l + 432 * 32;
    u16* wt3l = wt3h + 864 * 64;
    u16* wt4h = wt3l + 864 * 64;
    u16* wt4l = wt4h + 1728 * 128;
    u16* wt5h = wt4l + 1728 * 128;
    u16* wt5l = wt5h + (size_t)3456 * 512;
    u16* uend = wt5l + (size_t)3456 * 512;
    float* p4 = (float*)(((uintptr_t)uend + 15) & ~(uintptr_t)15);
    float* p5 = p4 + (size_t)2 * M4 * 128;

    zinit<<<1, 128, 0, stream>>>(zp);
    wsplit<<<cdiv(432 * 32, 256), 256, 0, stream>>>(W2, wt2h, wt2l, 432, 32);
    wsplit<<<cdiv(864 * 64, 256), 256, 0, stream>>>(W3, wt3h, wt3l, 864, 64);
    wsplit<<<cdiv(1728 * 128, 256), 256, 0, stream>>>(W4, wt4h, wt4l, 1728, 128);
    wsplit<<<cdiv(3456 * 512, 256), 256, 0, stream>>>(W5, wt5h, wt5l, 3456, 512);

    conv_l1<<<cdiv(M1, 64), 256, 0, stream>>>(feats, nm1, W1, x1, M1);

    // L2: 16 -> 32, waves 4x1 (WM=32, WN=32), KPER=14
    conv_lds<16, 32, 32, 4, 1, 1, true>
        <<<dim3(cdiv(M2, 128), 1, 1), 256, 0, stream>>>(
            x1, nm2, wt2h, wt2l, zp, nullptr, x2, M2);
    // L3: 32 -> 64, waves 2x2 (WM=64, WN=32), KPER=27
    conv_lds<32, 64, 64, 2, 2, 1, true>
        <<<dim3(cdiv(M3, 128), 1, 1), 256, 0, stream>>>(
            x2, nm3, wt3h, wt3l, zp, nullptr, x3, M3);
    // L4: 64 -> 128, waves 2x2, K-split 2, KPER=27
    conv_lds<64, 128, 64, 2, 2, 2, false>
        <<<dim3(cdiv(M4, 128), 2, 2), 256, 0, stream>>>(
            x3, nm4, wt4h, wt4l, zp, p4, nullptr, M4);
    reduce_bf<128><<<cdiv(M4 * 128, 256), 256, 0, stream>>>(p4, x4, M4 * 128, 2);
    // L5: 128 -> 512, waves 2x2, K-split 4, KPER=27
    conv_lds<128, 512, 64, 2, 2, 4, false>
        <<<dim3(cdiv(M5, 128), 8, 4), 256, 0, stream>>>(
            x4, nm5, wt5h, wt5l, zp, p5, nullptr, M5);
    reduce_f32<<<cdiv(M5 * 512 / 4, 256), 256, 0, stream>>>(p5, (float*)d_out, M5 * 512 / 4, 4);
}

// Round 6
// 195.281 us; speedup vs baseline: 1.1652x; 1.1067x over previous
//
#include <hip/hip_runtime.h>

typedef unsigned short u16;
typedef unsigned int u32;
typedef __attribute__((ext_vector_type(8))) short short8;
typedef __attribute__((ext_vector_type(4))) float float4v;

static inline int cdiv(int a, int b) { return (a + b - 1) / b; }

__device__ __forceinline__ u16 f2bf(float f) {
    u32 u = __float_as_uint(f);
    u = (u + 0x7fffu + ((u >> 16) & 1u)) >> 16;
    return (u16)u;
}
__device__ __forceinline__ float bf2f(u16 s) {
    return __uint_as_float(((u32)s) << 16);
}

typedef __attribute__((address_space(3))) u16 lds_u16;
typedef __attribute__((address_space(1))) const u16 glb_u16;
__device__ __forceinline__ void gl_lds16(const u16* g, u16* l) {
    __builtin_amdgcn_global_load_lds((glb_u16*)g, (lds_u16*)l, 16, 0, 0);
}

__global__ void zinit(u16* zp) { zp[threadIdx.x] = 0; }

// W (K rows, COUT cols) fp32 -> transposed bf16 interleaved [co][.. h8|l8 ..]
__global__ __launch_bounds__(256) void wsplit(
    const float* __restrict__ W, u16* __restrict__ wt, int K, int COUT)
{
    int e = blockIdx.x * 256 + threadIdx.x;
    if (e >= K * COUT) return;
    int kk = e / COUT, co = e % COUT;
    float w = W[e];
    u16 h = f2bf(w);
    u16 l = f2bf(w - bf2f(h));
    size_t base = (size_t)co * (2 * K) + ((kk >> 3) * 16) + (kk & 7);
    wt[base] = h;
    wt[base + 8] = l;
}

// ------ Layer 1: C_in=1 -> 16, k-split x4 in-block; interleaved h/l out ------
__global__ __launch_bounds__(256) void conv_l1(
    const float* __restrict__ feats, const int* __restrict__ nmap,
    const float* __restrict__ W, u16* __restrict__ o, int N)
{
    __shared__ float4 w4[27 * 4];
    __shared__ float part[4][64][17];
    for (int i = threadIdx.x; i < 27 * 4; i += 256)
        w4[i] = reinterpret_cast<const float4*>(W)[i];
    __syncthreads();

    const int tx = threadIdx.x & 63;
    const int tz = threadIdx.x >> 6;
    const int row = blockIdx.x * 64 + tx;

    float acc[16];
#pragma unroll
    for (int j = 0; j < 16; ++j) acc[j] = 0.f;

#pragma unroll
    for (int s = 0; s < 7; ++s) {
        int k = tz * 7 + s;
        if (k < 27) {
            int idx = (row < N) ? nmap[(size_t)k * N + row] : -1;
            float v = (idx >= 0) ? feats[idx] : 0.f;
#pragma unroll
            for (int cq = 0; cq < 4; ++cq) {
                float4 w = w4[k * 4 + cq];
                acc[cq * 4 + 0] = fmaf(v, w.x, acc[cq * 4 + 0]);
                acc[cq * 4 + 1] = fmaf(v, w.y, acc[cq * 4 + 1]);
                acc[cq * 4 + 2] = fmaf(v, w.z, acc[cq * 4 + 2]);
                acc[cq * 4 + 3] = fmaf(v, w.w, acc[cq * 4 + 3]);
            }
        }
    }
#pragma unroll
    for (int c = 0; c < 16; ++c) part[tz][tx][c] = acc[c];
    __syncthreads();

    const int r = threadIdx.x & 63;
    const int cs = (threadIdx.x >> 6) * 4;
    const int orow = blockIdx.x * 64 + r;
    if (orow >= N) return;
    float ov[4];
#pragma unroll
    for (int j = 0; j < 4; ++j) {
        float a = part[0][r][cs + j];
#pragma unroll
        for (int p = 1; p < 4; ++p) a += part[p][r][cs + j];
        ov[j] = a;
    }
    u32 h01 = (u32)f2bf(ov[0]) | ((u32)f2bf(ov[1]) << 16);
    u32 h23 = (u32)f2bf(ov[2]) | ((u32)f2bf(ov[3]) << 16);
    float l0 = ov[0] - bf2f(f2bf(ov[0])), l1 = ov[1] - bf2f(f2bf(ov[1]));
    float l2 = ov[2] - bf2f(f2bf(ov[2])), l3 = ov[3] - bf2f(f2bf(ov[3]));
    u32 g01 = (u32)f2bf(l0) | ((u32)f2bf(l1) << 16);
    u32 g23 = (u32)f2bf(l2) | ((u32)f2bf(l3) << 16);
    // interleaved row (32 u16): [h0-7, l0-7, h8-15, l8-15]
    int g = cs >> 3, p = cs & 7;
    *reinterpret_cast<uint2*>(o + (size_t)orow * 32 + g * 16 + p) = make_uint2(h01, h23);
    *reinterpret_cast<uint2*>(o + (size_t)orow * 32 + g * 16 + 8 + p) = make_uint2(g01, g23);
}

// ------ MFMA gathered GEMM: gl_lds A-gather, 2-deep counted-vmcnt pipeline ---
// x: [row][2*CIN] interleaved groups [h8|l8]. wt: [co][2*K] same interleave.
// LDS: 4 bufs x {h,l} planes x [BM rows][32 u16], chunk-swizzled (2-way free).
template<int CIN, int COUT, int BN, int WAVES_M, int WAVES_N, int KSPLIT, bool BFOUT>
__global__ __launch_bounds__(256) void conv_lds(
    const u16* __restrict__ x, const int* __restrict__ nmap,
    const u16* __restrict__ wt, const u16* __restrict__ zp,
    float* __restrict__ outf, u16* __restrict__ o, int N)
{
    constexpr int BM = 128;
    constexpr int K = 27 * CIN;
    constexpr int KSTEPS = (K + 31) / 32;
    static_assert(KSTEPS % KSPLIT == 0, "ksplit divides ksteps");
    constexpr int KPER = KSTEPS / KSPLIT;
    constexpr int WM = BM / WAVES_M, WN = BN / WAVES_N;
    static_assert(WAVES_M * WAVES_N == 4, "4 waves");
    constexpr int FM = WM / 16, FN = WN / 16;

    __shared__ __align__(16) u16 Asg[4][2][BM * 32];  // 64 KB

    const int lane = threadIdx.x & 63;
    const int wave = threadIdx.x >> 6;
    const int wm = wave / WAVES_N, wn = wave % WAVES_N;
    const int fr = lane & 15;
    const int kc = lane >> 4;
    const int row0 = blockIdx.x * BM;
    const int co0 = blockIdx.y * BN;
    const int ks0 = blockIdx.z * KPER;

    // staging geometry: wave covers chunks {wave*2, wave*2+1} x {h,l} planes
    int rowS[2], c4S[2];
#pragma unroll
    for (int t2 = 0; t2 < 2; ++t2) {
        int ch = wave * 2 + t2;
        rowS[t2] = ch * 16 + (lane >> 2);
        c4S[t2] = (lane & 3) ^ ((rowS[t2] >> 1) & 3);
    }
    // fragment LDS read offsets (u16, within one plane)
    int aoff[FM];
#pragma unroll
    for (int i = 0; i < FM; ++i) {
        int rt = wm * WM + i * 16 + fr;
        aoff[i] = rt * 32 + ((kc ^ ((rt >> 1) & 3)) * 8);
    }

    float4v acc[FM][FN];
#pragma unroll
    for (int i = 0; i < FM; ++i)
#pragma unroll
        for (int j = 0; j < FN; ++j) acc[i][j] = (float4v){0.f, 0.f, 0.f, 0.f};

    int idxq[4][2];
    short8 bh[3][FN], bl[3][FN];
    const short8 zero8 = (short8){0, 0, 0, 0, 0, 0, 0, 0};

    auto load_idx = [&](int s, int slot) {   // 2 vmem
#pragma unroll
        for (int t2 = 0; t2 < 2; ++t2) {
            int kk8 = (ks0 + s) * 32 + c4S[t2] * 8;
            int koff = kk8 / CIN; if (koff > 26) koff = 26;
            int r = row0 + rowS[t2];
            int rc = (r < N) ? r : (N - 1);
            int v = nmap[(size_t)koff * N + rc];
            idxq[slot][t2] = (r < N && kk8 < K) ? v : -1;
        }
    };
    auto stageA = [&](int s, int buf, int slot) {  // 4 vmem (gl_lds)
#pragma unroll
        for (int t2 = 0; t2 < 2; ++t2) {
            int kk8 = (ks0 + s) * 32 + c4S[t2] * 8;
            int cg = (kk8 & (CIN - 1)) >> 3;
            int idx = idxq[slot][t2];
            const u16* sh = (idx >= 0) ? (x + (size_t)idx * (2 * CIN) + cg * 16) : zp;
            const u16* sl = (idx >= 0) ? (sh + 8) : zp;
            int ch = wave * 2 + t2;
            gl_lds16(sh, &Asg[buf][0][ch * 512]);
            gl_lds16(sl, &Asg[buf][1][ch * 512]);
        }
    };
    auto loadB = [&](int s, int slot) {      // 2*FN vmem
        int kkb = (ks0 + s) * 32 + kc * 8;
        bool ok = (kkb < K);
#pragma unroll
        for (int j = 0; j < FN; ++j) {
            const u16* bp = wt + (size_t)(co0 + wn * WN + j * 16 + fr) * (2 * K)
                               + (size_t)((ks0 + s) * 4 + kc) * 16;
            bh[slot][j] = ok ? *reinterpret_cast<const short8*>(bp) : zero8;
            bl[slot][j] = ok ? *reinterpret_cast<const short8*>(bp + 8) : zero8;
        }
    };
    auto mm = [&](int buf, int slot) {
        short8 ah[FM], al[FM];
#pragma unroll
        for (int i = 0; i < FM; ++i) {
            ah[i] = *reinterpret_cast<const short8*>(&Asg[buf][0][aoff[i]]);
            al[i] = *reinterpret_cast<const short8*>(&Asg[buf][1][aoff[i]]);
        }
#pragma unroll
        for (int i = 0; i < FM; ++i)
#pragma unroll
            for (int j = 0; j < FN; ++j) {
                acc[i][j] = __builtin_amdgcn_mfma_f32_16x16x32_bf16(ah[i], bh[slot][j], acc[i][j], 0, 0, 0);
                acc[i][j] = __builtin_amdgcn_mfma_f32_16x16x32_bf16(ah[i], bl[slot][j], acc[i][j], 0, 0, 0);
                acc[i][j] = __builtin_amdgcn_mfma_f32_16x16x32_bf16(al[i], bh[slot][j], acc[i][j], 0, 0, 0);
            }
    };
    // vmem issued at iter t (program order pinned by clobber asm at each wait)
    auto iss = [&](int t) { return (t + 2 < KPER) ? (((t + 4 < KPER) ? 2 : 0) + 4 + 2 * FN) : 0; };

    // prologue
    load_idx(0, 0); load_idx(1, 1); load_idx(2, 2); load_idx(3, 3);
    asm volatile("" ::: "memory");
    stageA(0, 0, 0); loadB(0, 0);
    asm volatile("" ::: "memory");
    stageA(1, 1, 1); loadB(1, 1);

#pragma unroll
    for (int s = 0; s < KPER; ++s) {
        if (s + 2 < KPER) {
            if (s + 4 < KPER) load_idx(s + 4, (s + 4) & 3);
            stageA(s + 2, (s + 2) & 3, (s + 2) & 3);
            loadB(s + 2, (s + 2) % 3);
            int n = (s == 0) ? ((4 + 4 + 2 * FN) + iss(0)) : ((2 * FN) + iss(s - 1) + iss(s));
            if (n >= 24)      asm volatile("s_waitcnt vmcnt(24)" ::: "memory");
            else if (n >= 16) asm volatile("s_waitcnt vmcnt(16)" ::: "memory");
            else              asm volatile("s_waitcnt vmcnt(8)" ::: "memory");
        } else {
            asm volatile("s_waitcnt vmcnt(0)" ::: "memory");
        }
        __builtin_amdgcn_s_barrier();
        asm volatile("" ::: "memory");
        mm(s & 3, s % 3);
    }

    // epilogue: D row=(lane>>4)*4+q, col=lane&15 (m89)
    const int orow0 = row0 + wm * WM + (lane >> 4) * 4;
    const int ocol0 = co0 + wn * WN + fr;
#pragma unroll
    for (int i = 0; i < FM; ++i)
#pragma unroll
        for (int j = 0; j < FN; ++j)
#pragma unroll
            for (int qq = 0; qq < 4; ++qq) {
                int r = orow0 + i * 16 + qq;
                int c = ocol0 + j * 16;
                if (r < N) {
                    float v = acc[i][j][qq];
                    if constexpr (BFOUT) {
                        u16 h = f2bf(v);
                        size_t base = (size_t)r * (2 * COUT) + ((c >> 3) * 16) + (c & 7);
                        o[base] = h;
                        o[base + 8] = f2bf(v - bf2f(h));
                    } else {
                        outf[(size_t)blockIdx.z * N * COUT + (size_t)r * COUT + c] = v;
                    }
                }
            }
}

// ------ deterministic fixed-order K-split reductions ------
__global__ __launch_bounds__(256) void reduce_f32(
    const float* __restrict__ p, float* __restrict__ out, int m4, int S)
{
    int i = blockIdx.x * 256 + threadIdx.x;
    if (i >= m4) return;
    const float4* p4 = reinterpret_cast<const float4*>(p);
    float4 a = p4[i];
    for (int s = 1; s < S; ++s) {
        float4 v = p4[(size_t)s * m4 + i];
        a.x += v.x; a.y += v.y; a.z += v.z; a.w += v.w;
    }
    reinterpret_cast<float4*>(out)[i] = a;
}
template<int C>
__global__ __launch_bounds__(256) void reduce_bf(
    const float* __restrict__ p, u16* __restrict__ o, int m, int S)
{
    int i = blockIdx.x * 256 + threadIdx.x;
    if (i >= m) return;
    float a = p[i];
    for (int s = 1; s < S; ++s) a += p[(size_t)s * m + i];
    int r = i / C, c = i % C;
    u16 h = f2bf(a);
    size_t base = (size_t)r * (2 * C) + ((c >> 3) * 16) + (c & 7);
    o[base] = h;
    o[base + 8] = f2bf(a - bf2f(h));
}

extern "C" void kernel_launch(void* const* d_in, const int* in_sizes, int n_in,
                              void* d_out, int out_size, void* d_ws, size_t ws_size,
                              hipStream_t stream)
{
    const float* feats = (const float*)d_in[0];
    const float* W1 = (const float*)d_in[1];
    const int*   nm1 = (const int*)d_in[2];
    const float* W2 = (const float*)d_in[3];
    const int*   nm2 = (const int*)d_in[4];
    const float* W3 = (const float*)d_in[5];
    const int*   nm3 = (const int*)d_in[6];
    const float* W4 = (const float*)d_in[7];
    const int*   nm4 = (const int*)d_in[8];
    const float* W5 = (const float*)d_in[9];
    const int*   nm5 = (const int*)d_in[10];

    const int M1 = in_sizes[2] / 27;
    const int M2 = in_sizes[4] / 27;
    const int M3 = in_sizes[6] / 27;
    const int M4 = in_sizes[8] / 27;
    const int M5 = in_sizes[10] / 27;

    u16* zp = (u16*)d_ws;                        // 128 u16 zero page
    u16* x1 = zp + 128;                          // M1 x 32
    u16* x2 = x1 + (size_t)M1 * 32;              // M2 x 64
    u16* x3 = x2 + (size_t)M2 * 64;              // M3 x 128
    u16* x4 = x3 + (size_t)M3 * 128;             // M4 x 256
    u16* wt2 = x4 + (size_t)M4 * 256;            // 32 x 864
    u16* wt3 = wt2 + 32 * 864;                   // 64 x 1728
    u16* wt4 = wt3 + (size_t)64 * 1728;          // 128 x 3456
    u16* wt5 = wt4 + (size_t)128 * 3456;         // 512 x 6912
    // partial buffers alias dead regions: p4 on x1 (dead after L2),
    // p5 on x2 (dead after L3)
    float* p4 = (float*)x1;                      // 6 x M4*128 f32 = 12.6 MB <= 22.7
    float* p5 = (float*)x2;                      // 12 x M5*512 f32 = 12.6 MB <= 25.6

    zinit<<<1, 128, 0, stream>>>(zp);
    wsplit<<<cdiv(432 * 32, 256), 256, 0, stream>>>(W2, wt2, 432, 32);
    wsplit<<<cdiv(864 * 64, 256), 256, 0, stream>>>(W3, wt3, 864, 64);
    wsplit<<<cdiv(1728 * 128, 256), 256, 0, stream>>>(W4, wt4, 1728, 128);
    wsplit<<<cdiv(3456 * 512, 256), 256, 0, stream>>>(W5, wt5, 3456, 512);

    conv_l1<<<cdiv(M1, 64), 256, 0, stream>>>(feats, nm1, W1, x1, M1);

    // L2: 16 -> 32, waves 4x1 (WM=32,WN=32), KPER=14
    conv_lds<16, 32, 32, 4, 1, 1, true>
        <<<dim3(cdiv(M2, 128), 1, 1), 256, 0, stream>>>(
            x1, nm2, wt2, zp, nullptr, x2, M2);
    // L3: 32 -> 64, waves 2x2 (WM=64,WN=32), KPER=27
    conv_lds<32, 64, 64, 2, 2, 1, true>
        <<<dim3(cdiv(M3, 128), 1, 1), 256, 0, stream>>>(
            x2, nm3, wt3, zp, nullptr, x3, M3);
    // L4: 64 -> 128, waves 2x2, K-split 6 (KPER=9), 384 blocks
    conv_lds<64, 128, 64, 2, 2, 6, false>
        <<<dim3(cdiv(M4, 128), 2, 6), 256, 0, stream>>>(
            x3, nm4, wt4, zp, p4, nullptr, M4);
    reduce_bf<128><<<cdiv(M4 * 128, 256), 256, 0, stream>>>(p4, x4, M4 * 128, 6);
    // L5: 128 -> 512, waves 2x2, K-split 12 (KPER=9), 384 blocks
    conv_lds<128, 512, 64, 2, 2, 12, false>
        <<<dim3(cdiv(M5, 128), 8, 12), 256, 0, stream>>>(
            x4, nm5, wt5, zp, p5, nullptr, M5);
    reduce_f32<<<cdiv(M5 * 512 / 4, 256), 256, 0, stream>>>(p5, (float*)d_out, M5 * 512 / 4, 12);
}

// Round 7
// 175.857 us; speedup vs baseline: 1.2939x; 1.1105x over previous
//
#include <hip/hip_runtime.h>

typedef unsigned short u16;
typedef unsigned int u32;
typedef __attribute__((ext_vector_type(8))) short short8;
typedef __attribute__((ext_vector_type(4))) float float4v;

static inline int cdiv(int a, int b) { return (a + b - 1) / b; }

__device__ __forceinline__ u16 f2bf(float f) {
    u32 u = __float_as_uint(f);
    u = (u + 0x7fffu + ((u >> 16) & 1u)) >> 16;
    return (u16)u;
}
__device__ __forceinline__ float bf2f(u16 s) {
    return __uint_as_float(((u32)s) << 16);
}

// W ([K][COUT] fp32) -> bf16 hi/lo, k-group-major: wt[(g*COUT + co)*16 + (k&7)]
// h at +0..7, l at +8..15  (g = k>>3). B-frag loads coalesce across co lanes.
__global__ __launch_bounds__(256) void wsplit(
    const float* __restrict__ W, u16* __restrict__ wt, int K, int COUT)
{
    int e = blockIdx.x * 256 + threadIdx.x;
    if (e >= K * COUT) return;
    int kk = e / COUT, co = e % COUT;
    float w = W[e];
    u16 h = f2bf(w);
    u16 l = f2bf(w - bf2f(h));
    size_t base = ((size_t)(kk >> 3) * COUT + co) * 16 + (kk & 7);
    wt[base] = h;
    wt[base + 8] = l;
}

// ------ Layer 1: C_in=1 -> 16. 4 threads/row x 4 channels, rolled k ------
__global__ __launch_bounds__(256) void conv_l1(
    const float* __restrict__ feats, const int* __restrict__ nmap,
    const float* __restrict__ W, u16* __restrict__ o, int N)
{
    __shared__ float4 w4[27 * 4];
    for (int i = threadIdx.x; i < 27 * 4; i += 256)
        w4[i] = reinterpret_cast<const float4*>(W)[i];
    __syncthreads();

    const int r = threadIdx.x & 63;
    const int cq = threadIdx.x >> 6;       // channel quad 0..3
    const int row = blockIdx.x * 64 + r;
    if (row >= N) return;

    float a0 = 0.f, a1 = 0.f, a2 = 0.f, a3 = 0.f;
#pragma unroll 3
    for (int k = 0; k < 27; ++k) {
        int idx = nmap[(size_t)k * N + row];
        float v = (idx >= 0) ? feats[idx] : 0.f;
        float4 w = w4[k * 4 + cq];
        a0 = fmaf(v, w.x, a0);
        a1 = fmaf(v, w.y, a1);
        a2 = fmaf(v, w.z, a2);
        a3 = fmaf(v, w.w, a3);
    }
    u16 h0 = f2bf(a0), h1 = f2bf(a1), h2 = f2bf(a2), h3 = f2bf(a3);
    u32 h01 = (u32)h0 | ((u32)h1 << 16);
    u32 h23 = (u32)h2 | ((u32)h3 << 16);
    u32 l01 = (u32)f2bf(a0 - bf2f(h0)) | ((u32)f2bf(a1 - bf2f(h1)) << 16);
    u32 l23 = (u32)f2bf(a2 - bf2f(h2)) | ((u32)f2bf(a3 - bf2f(h3)) << 16);
    // row layout (32 u16): [h0-7, l0-7, h8-15, l8-15]
    int g = cq >> 1, p = (cq & 1) * 4;
    *reinterpret_cast<uint2*>(o + (size_t)row * 32 + g * 16 + p) = make_uint2(h01, h23);
    *reinterpret_cast<uint2*>(o + (size_t)row * 32 + g * 16 + 8 + p) = make_uint2(l01, l23);
}

// ------ 1-wave direct-fragment MFMA gathered GEMM (no LDS, no barriers) -----
// x: [row][2*CIN] u16, per 8-k group [h8|l8]. wt: k-group-major (see wsplit).
// Wave tile 32x32 (FM=FN=2). Depth-2 frag buffers, depth-3 idx ring,
// fully unrolled K so all indices are compile-time.
template<int CIN, int COUT, int KSPLIT, bool BFOUT>
__global__ __launch_bounds__(64, 4) void conv_direct(
    const u16* __restrict__ x, const int* __restrict__ nmap,
    const u16* __restrict__ wt,
    float* __restrict__ outf, u16* __restrict__ o, int N)
{
    constexpr int K = 27 * CIN;
    constexpr int KSTEPS = (K + 31) / 32;
    constexpr int KPER = (KSTEPS + KSPLIT - 1) / KSPLIT;
    static_assert(KPER * KSPLIT >= KSTEPS, "");

    const int lane = threadIdx.x;
    const int fr = lane & 15;
    const int kc = lane >> 4;
    const int row0 = blockIdx.x * 32;
    const int co0 = blockIdx.y * 32;
    const int ks0 = blockIdx.z * KPER;

    float4v acc[2][2];
#pragma unroll
    for (int i = 0; i < 2; ++i)
#pragma unroll
        for (int j = 0; j < 2; ++j) acc[i][j] = (float4v){0.f, 0.f, 0.f, 0.f};

    int idxq[3][2];
    short8 ah[2][2], al[2][2], bh[2][2], bl[2][2];
    const short8 zero8 = (short8){0, 0, 0, 0, 0, 0, 0, 0};

    auto load_idx = [&](int s, int slot) {
        int kk8 = (ks0 + s) * 32 + kc * 8;
        int koff = kk8 / CIN;
#pragma unroll
        for (int i = 0; i < 2; ++i) {
            int r = row0 + i * 16 + fr;
            idxq[slot][i] = (kk8 < K && r < N) ? nmap[(size_t)koff * N + r] : -1;
        }
    };
    auto load_frag = [&](int s, int islot, int p) {
        int kk8 = (ks0 + s) * 32 + kc * 8;
        int cg = (kk8 & (CIN - 1)) >> 3;
#pragma unroll
        for (int i = 0; i < 2; ++i) {
            int idx = idxq[islot][i];
            if (idx >= 0) {
                const u16* base = x + (size_t)idx * (2 * CIN) + cg * 16;
                ah[p][i] = *reinterpret_cast<const short8*>(base);
                al[p][i] = *reinterpret_cast<const short8*>(base + 8);
            } else {
                ah[p][i] = zero8;
                al[p][i] = zero8;
            }
        }
        int g = (ks0 + s) * 4 + kc;
        bool ok = (g * 8) < K;
#pragma unroll
        for (int j = 0; j < 2; ++j) {
            const u16* bp = wt + ((size_t)g * COUT + (co0 + j * 16 + fr)) * 16;
            bh[p][j] = ok ? *reinterpret_cast<const short8*>(bp) : zero8;
            bl[p][j] = ok ? *reinterpret_cast<const short8*>(bp + 8) : zero8;
        }
    };
    auto mm = [&](int p) {
#pragma unroll
        for (int i = 0; i < 2; ++i)
#pragma unroll
            for (int j = 0; j < 2; ++j) {
                acc[i][j] = __builtin_amdgcn_mfma_f32_16x16x32_bf16(ah[p][i], bh[p][j], acc[i][j], 0, 0, 0);
                acc[i][j] = __builtin_amdgcn_mfma_f32_16x16x32_bf16(ah[p][i], bl[p][j], acc[i][j], 0, 0, 0);
                acc[i][j] = __builtin_amdgcn_mfma_f32_16x16x32_bf16(al[p][i], bh[p][j], acc[i][j], 0, 0, 0);
            }
    };

    load_idx(0, 0);
    if (KPER > 1) load_idx(1, 1);
    if (KPER > 2) load_idx(2, 2);
    load_frag(0, 0, 0);
#pragma unroll
    for (int s = 0; s < KPER; ++s) {
        if (s + 3 < KPER) load_idx(s + 3, (s + 3) % 3);
        if (s + 1 < KPER) load_frag(s + 1, (s + 1) % 3, (s + 1) & 1);
        mm(s & 1);
    }

    // D layout: row=(lane>>4)*4+q, col=lane&15 (m89)
    const int orow0 = row0 + (lane >> 4) * 4;
    const int ocol0 = co0 + fr;
#pragma unroll
    for (int i = 0; i < 2; ++i)
#pragma unroll
        for (int j = 0; j < 2; ++j)
#pragma unroll
            for (int q = 0; q < 4; ++q) {
                int r = orow0 + i * 16 + q;
                int c = ocol0 + j * 16;
                if (r < N) {
                    float v = acc[i][j][q];
                    if constexpr (BFOUT) {
                        u16 h = f2bf(v);
                        size_t base = (size_t)r * (2 * COUT) + ((c >> 3) * 16) + (c & 7);
                        o[base] = h;
                        o[base + 8] = f2bf(v - bf2f(h));
                    } else {
                        outf[(size_t)blockIdx.z * N * COUT + (size_t)r * COUT + c] = v;
                    }
                }
            }
}

// ------ deterministic fixed-order K-split reductions ------
__global__ __launch_bounds__(256) void reduce_f32(
    const float* __restrict__ p, float* __restrict__ out, int m4, int S)
{
    int i = blockIdx.x * 256 + threadIdx.x;
    if (i >= m4) return;
    const float4* p4 = reinterpret_cast<const float4*>(p);
    float4 a = p4[i];
    for (int s = 1; s < S; ++s) {
        float4 v = p4[(size_t)s * m4 + i];
        a.x += v.x; a.y += v.y; a.z += v.z; a.w += v.w;
    }
    reinterpret_cast<float4*>(out)[i] = a;
}
template<int C>
__global__ __launch_bounds__(256) void reduce_bf(
    const float* __restrict__ p, u16* __restrict__ o, int m, int S)
{
    int i = blockIdx.x * 256 + threadIdx.x;
    if (i >= m) return;
    float a = p[i];
    for (int s = 1; s < S; ++s) a += p[(size_t)s * m + i];
    int r = i / C, c = i % C;
    u16 h = f2bf(a);
    size_t base = (size_t)r * (2 * C) + ((c >> 3) * 16) + (c & 7);
    o[base] = h;
    o[base + 8] = f2bf(a - bf2f(h));
}

extern "C" void kernel_launch(void* const* d_in, const int* in_sizes, int n_in,
                              void* d_out, int out_size, void* d_ws, size_t ws_size,
                              hipStream_t stream)
{
    const float* feats = (const float*)d_in[0];
    const float* W1 = (const float*)d_in[1];
    const int*   nm1 = (const int*)d_in[2];
    const float* W2 = (const float*)d_in[3];
    const int*   nm2 = (const int*)d_in[4];
    const float* W3 = (const float*)d_in[5];
    const int*   nm3 = (const int*)d_in[6];
    const float* W4 = (const float*)d_in[7];
    const int*   nm4 = (const int*)d_in[8];
    const float* W5 = (const float*)d_in[9];
    const int*   nm5 = (const int*)d_in[10];

    const int M1 = in_sizes[2] / 27;
    const int M2 = in_sizes[4] / 27;
    const int M3 = in_sizes[6] / 27;
    const int M4 = in_sizes[8] / 27;
    const int M5 = in_sizes[10] / 27;

    u16* x1 = (u16*)d_ws;                        // M1 x 32
    u16* x2 = x1 + (size_t)M1 * 32;              // M2 x 64
    u16* x3 = x2 + (size_t)M2 * 64;              // M3 x 128
    u16* x4 = x3 + (size_t)M3 * 128;             // M4 x 256
    u16* wt2 = x4 + (size_t)M4 * 256;            // 2*432*32
    u16* wt3 = wt2 + 2 * 432 * 32;               // 2*864*64
    u16* wt4 = wt3 + 2 * 864 * 64;               // 2*1728*128
    u16* wt5 = wt4 + 2 * 1728 * 128;             // 2*3456*512
    // partials alias dead regions (p4 on x1: dead after L2; p5 on x2: dead after L3)
    float* p4 = (float*)x1;                      // 2 * M4*128 f32
    float* p5 = (float*)x2;                      // 4 * M5*512 f32

    wsplit<<<cdiv(432 * 32, 256), 256, 0, stream>>>(W2, wt2, 432, 32);
    wsplit<<<cdiv(864 * 64, 256), 256, 0, stream>>>(W3, wt3, 864, 64);
    wsplit<<<cdiv(1728 * 128, 256), 256, 0, stream>>>(W4, wt4, 1728, 128);
    wsplit<<<cdiv(3456 * 512, 256), 256, 0, stream>>>(W5, wt5, 3456, 512);

    conv_l1<<<cdiv(M1, 64), 256, 0, stream>>>(feats, nm1, W1, x1, M1);

    // L2: 16 -> 32, KPER=14
    conv_direct<16, 32, 1, true>
        <<<dim3(cdiv(M2, 32), 1, 1), 64, 0, stream>>>(
            x1, nm2, wt2, nullptr, x2, M2);
    // L3: 32 -> 64, KPER=27
    conv_direct<32, 64, 1, true>
        <<<dim3(cdiv(M3, 32), 2, 1), 64, 0, stream>>>(
            x2, nm3, wt3, nullptr, x3, M3);
    // L4: 64 -> 128, K-split 2 (KPER=27)
    conv_direct<64, 128, 2, false>
        <<<dim3(cdiv(M4, 32), 4, 2), 64, 0, stream>>>(
            x3, nm4, wt4, p4, nullptr, M4);
    reduce_bf<128><<<cdiv(M4 * 128, 256), 256, 0, stream>>>(p4, x4, M4 * 128, 2);
    // L5: 128 -> 512, K-split 4 (KPER=27)
    conv_direct<128, 512, 4, false>
        <<<dim3(cdiv(M5, 32), 16, 4), 64, 0, stream>>>(
            x4, nm5, wt5, p5, nullptr, M5);
    reduce_f32<<<cdiv(M5 * 512 / 4, 256), 256, 0, stream>>>(p5, (float*)d_out, M5 * 512 / 4, 4);
}

// Round 8
// 153.931 us; speedup vs baseline: 1.4782x; 1.1424x over previous
//
#include <hip/hip_runtime.h>

typedef unsigned short u16;
typedef unsigned int u32;
typedef __attribute__((ext_vector_type(8))) short short8;
typedef __attribute__((ext_vector_type(4))) float float4v;

static inline int cdiv(int a, int b) { return (a + b - 1) / b; }

__device__ __forceinline__ u16 f2bf(float f) {
    u32 u = __float_as_uint(f);
    u = (u + 0x7fffu + ((u >> 16) & 1u)) >> 16;
    return (u16)u;
}
__device__ __forceinline__ float bf2f(u16 s) {
    return __uint_as_float(((u32)s) << 16);
}

// W ([K][COUT] fp32) -> bf16 hi/lo, k-group-major: wt[(g*COUT + co)*16 + (k&7)]
// h at +0..7, l at +8..15  (g = k>>3). B-frag loads coalesce across co lanes.
__global__ __launch_bounds__(256) void wsplit(
    const float* __restrict__ W, u16* __restrict__ wt, int K, int COUT)
{
    int e = blockIdx.x * 256 + threadIdx.x;
    if (e >= K * COUT) return;
    int kk = e / COUT, co = e % COUT;
    float w = W[e];
    u16 h = f2bf(w);
    u16 l = f2bf(w - bf2f(h));
    size_t base = ((size_t)(kk >> 3) * COUT + co) * 16 + (kk & 7);
    wt[base] = h;
    wt[base + 8] = l;
}

// ------ Layer 1: C_in=1 -> 16. ONE thread per row (no redundant gathers) ----
__global__ __launch_bounds__(256) void conv_l1(
    const float* __restrict__ feats, const int* __restrict__ nmap,
    const float* __restrict__ W, u16* __restrict__ o, int N)
{
    __shared__ float4 w4[27 * 4];
    for (int i = threadIdx.x; i < 27 * 4; i += 256)
        w4[i] = reinterpret_cast<const float4*>(W)[i];
    __syncthreads();

    const int row = blockIdx.x * 256 + threadIdx.x;
    if (row >= N) return;

    float acc[16];
#pragma unroll
    for (int j = 0; j < 16; ++j) acc[j] = 0.f;

#pragma unroll 3
    for (int k = 0; k < 27; ++k) {
        int idx = nmap[(size_t)k * N + row];
        float v = (idx >= 0) ? feats[idx] : 0.f;
#pragma unroll
        for (int cq = 0; cq < 4; ++cq) {
            float4 w = w4[k * 4 + cq];   // uniform address -> LDS broadcast
            acc[cq * 4 + 0] = fmaf(v, w.x, acc[cq * 4 + 0]);
            acc[cq * 4 + 1] = fmaf(v, w.y, acc[cq * 4 + 1]);
            acc[cq * 4 + 2] = fmaf(v, w.z, acc[cq * 4 + 2]);
            acc[cq * 4 + 3] = fmaf(v, w.w, acc[cq * 4 + 3]);
        }
    }

    // row layout (32 u16): [h0-7, l0-7, h8-15, l8-15]; 4 x 16B coalesced stores
    u16* op = o + (size_t)row * 32;
#pragma unroll
    for (int g = 0; g < 2; ++g) {
        u32 hw[4], lw[4];
#pragma unroll
        for (int p = 0; p < 4; ++p) {
            float v0 = acc[g * 8 + 2 * p], v1 = acc[g * 8 + 2 * p + 1];
            u16 h0 = f2bf(v0), h1 = f2bf(v1);
            hw[p] = (u32)h0 | ((u32)h1 << 16);
            lw[p] = (u32)f2bf(v0 - bf2f(h0)) | ((u32)f2bf(v1 - bf2f(h1)) << 16);
        }
        *reinterpret_cast<uint4*>(op + g * 16) = make_uint4(hw[0], hw[1], hw[2], hw[3]);
        *reinterpret_cast<uint4*>(op + g * 16 + 8) = make_uint4(lw[0], lw[1], lw[2], lw[3]);
    }
}

// ------ 1-wave direct-fragment MFMA gathered GEMM (no LDS, no barriers) -----
// x: [row][2*CIN] u16, per 8-k group [h8|l8]. wt: k-group-major (see wsplit).
// Wave tile 32x32 (FM=FN=2). Depth-2 frag buffers, depth-3 idx ring,
// fully unrolled K so all indices are compile-time.
template<int CIN, int COUT, int KSPLIT, bool BFOUT>
__global__ __launch_bounds__(64, 4) void conv_direct(
    const u16* __restrict__ x, const int* __restrict__ nmap,
    const u16* __restrict__ wt,
    float* __restrict__ outf, u16* __restrict__ o, int N)
{
    constexpr int K = 27 * CIN;
    constexpr int KSTEPS = (K + 31) / 32;
    constexpr int KPER = (KSTEPS + KSPLIT - 1) / KSPLIT;
    static_assert(KPER * KSPLIT >= KSTEPS, "");

    const int lane = threadIdx.x;
    const int fr = lane & 15;
    const int kc = lane >> 4;
    const int row0 = blockIdx.x * 32;
    const int co0 = blockIdx.y * 32;
    const int ks0 = blockIdx.z * KPER;

    float4v acc[2][2];
#pragma unroll
    for (int i = 0; i < 2; ++i)
#pragma unroll
        for (int j = 0; j < 2; ++j) acc[i][j] = (float4v){0.f, 0.f, 0.f, 0.f};

    int idxq[3][2];
    short8 ah[2][2], al[2][2], bh[2][2], bl[2][2];
    const short8 zero8 = (short8){0, 0, 0, 0, 0, 0, 0, 0};

    auto load_idx = [&](int s, int slot) {
        int kk8 = (ks0 + s) * 32 + kc * 8;
        int koff = kk8 / CIN;
#pragma unroll
        for (int i = 0; i < 2; ++i) {
            int r = row0 + i * 16 + fr;
            idxq[slot][i] = (kk8 < K && r < N) ? nmap[(size_t)koff * N + r] : -1;
        }
    };
    auto load_frag = [&](int s, int islot, int p) {
        int kk8 = (ks0 + s) * 32 + kc * 8;
        int cg = (kk8 & (CIN - 1)) >> 3;
#pragma unroll
        for (int i = 0; i < 2; ++i) {
            int idx = idxq[islot][i];
            if (idx >= 0) {
                const u16* base = x + (size_t)idx * (2 * CIN) + cg * 16;
                ah[p][i] = *reinterpret_cast<const short8*>(base);
                al[p][i] = *reinterpret_cast<const short8*>(base + 8);
            } else {
                ah[p][i] = zero8;
                al[p][i] = zero8;
            }
        }
        int g = (ks0 + s) * 4 + kc;
        bool ok = (g * 8) < K;
#pragma unroll
        for (int j = 0; j < 2; ++j) {
            const u16* bp = wt + ((size_t)g * COUT + (co0 + j * 16 + fr)) * 16;
            bh[p][j] = ok ? *reinterpret_cast<const short8*>(bp) : zero8;
            bl[p][j] = ok ? *reinterpret_cast<const short8*>(bp + 8) : zero8;
        }
    };
    auto mm = [&](int p) {
#pragma unroll
        for (int i = 0; i < 2; ++i)
#pragma unroll
            for (int j = 0; j < 2; ++j) {
                acc[i][j] = __builtin_amdgcn_mfma_f32_16x16x32_bf16(ah[p][i], bh[p][j], acc[i][j], 0, 0, 0);
                acc[i][j] = __builtin_amdgcn_mfma_f32_16x16x32_bf16(ah[p][i], bl[p][j], acc[i][j], 0, 0, 0);
                acc[i][j] = __builtin_amdgcn_mfma_f32_16x16x32_bf16(al[p][i], bh[p][j], acc[i][j], 0, 0, 0);
            }
    };

    load_idx(0, 0);
    if (KPER > 1) load_idx(1, 1);
    if (KPER > 2) load_idx(2, 2);
    load_frag(0, 0, 0);
#pragma unroll
    for (int s = 0; s < KPER; ++s) {
        if (s + 3 < KPER) load_idx(s + 3, (s + 3) % 3);
        if (s + 1 < KPER) load_frag(s + 1, (s + 1) % 3, (s + 1) & 1);
        mm(s & 1);
    }

    // D layout: row=(lane>>4)*4+q, col=lane&15 (m89)
    const int orow0 = row0 + (lane >> 4) * 4;
    const int ocol0 = co0 + fr;
#pragma unroll
    for (int i = 0; i < 2; ++i)
#pragma unroll
        for (int j = 0; j < 2; ++j)
#pragma unroll
            for (int q = 0; q < 4; ++q) {
                int r = orow0 + i * 16 + q;
                int c = ocol0 + j * 16;
                if (r < N) {
                    float v = acc[i][j][q];
                    if constexpr (BFOUT) {
                        u16 h = f2bf(v);
                        size_t base = (size_t)r * (2 * COUT) + ((c >> 3) * 16) + (c & 7);
                        o[base] = h;
                        o[base + 8] = f2bf(v - bf2f(h));
                    } else {
                        outf[(size_t)blockIdx.z * N * COUT + (size_t)r * COUT + c] = v;
                    }
                }
            }
}

// ------ deterministic fixed-order K-split reductions ------
__global__ __launch_bounds__(256) void reduce_f32(
    const float* __restrict__ p, float* __restrict__ out, int m4, int S)
{
    int i = blockIdx.x * 256 + threadIdx.x;
    if (i >= m4) return;
    const float4* p4 = reinterpret_cast<const float4*>(p);
    float4 a = p4[i];
    for (int s = 1; s < S; ++s) {
        float4 v = p4[(size_t)s * m4 + i];
        a.x += v.x; a.y += v.y; a.z += v.z; a.w += v.w;
    }
    reinterpret_cast<float4*>(out)[i] = a;
}
template<int C>
__global__ __launch_bounds__(256) void reduce_bf(
    const float* __restrict__ p, u16* __restrict__ o, int m, int S)
{
    int i = blockIdx.x * 256 + threadIdx.x;
    if (i >= m) return;
    float a = p[i];
    for (int s = 1; s < S; ++s) a += p[(size_t)s * m + i];
    int r = i / C, c = i % C;
    u16 h = f2bf(a);
    size_t base = (size_t)r * (2 * C) + ((c >> 3) * 16) + (c & 7);
    o[base] = h;
    o[base + 8] = f2bf(a - bf2f(h));
}

extern "C" void kernel_launch(void* const* d_in, const int* in_sizes, int n_in,
                              void* d_out, int out_size, void* d_ws, size_t ws_size,
                              hipStream_t stream)
{
    const float* feats = (const float*)d_in[0];
    const float* W1 = (const float*)d_in[1];
    const int*   nm1 = (const int*)d_in[2];
    const float* W2 = (const float*)d_in[3];
    const int*   nm2 = (const int*)d_in[4];
    const float* W3 = (const float*)d_in[5];
    const int*   nm3 = (const int*)d_in[6];
    const float* W4 = (const float*)d_in[7];
    const int*   nm4 = (const int*)d_in[8];
    const float* W5 = (const float*)d_in[9];
    const int*   nm5 = (const int*)d_in[10];

    const int M1 = in_sizes[2] / 27;
    const int M2 = in_sizes[4] / 27;
    const int M3 = in_sizes[6] / 27;
    const int M4 = in_sizes[8] / 27;
    const int M5 = in_sizes[10] / 27;

    u16* x1 = (u16*)d_ws;                        // M1 x 32
    u16* x2 = x1 + (size_t)M1 * 32;              // M2 x 64
    u16* x3 = x2 + (size_t)M2 * 64;              // M3 x 128
    u16* x4 = x3 + (size_t)M3 * 128;             // M4 x 256
    u16* wt2 = x4 + (size_t)M4 * 256;            // 2*432*32
    u16* wt3 = wt2 + 2 * 432 * 32;               // 2*864*64
    u16* wt4 = wt3 + 2 * 864 * 64;               // 2*1728*128
    u16* wt5 = wt4 + 2 * 1728 * 128;             // 2*3456*512
    // partials alias dead regions (p4 on x1: dead after L2; p5 on x2: dead after L3)
    float* p4 = (float*)x1;                      // 2 * M4*128 f32
    float* p5 = (float*)x2;                      // 4 * M5*512 f32

    wsplit<<<cdiv(432 * 32, 256), 256, 0, stream>>>(W2, wt2, 432, 32);
    wsplit<<<cdiv(864 * 64, 256), 256, 0, stream>>>(W3, wt3, 864, 64);
    wsplit<<<cdiv(1728 * 128, 256), 256, 0, stream>>>(W4, wt4, 1728, 128);
    wsplit<<<cdiv(3456 * 512, 256), 256, 0, stream>>>(W5, wt5, 3456, 512);

    conv_l1<<<cdiv(M1, 256), 256, 0, stream>>>(feats, nm1, W1, x1, M1);

    // L2: 16 -> 32, KPER=14
    conv_direct<16, 32, 1, true>
        <<<dim3(cdiv(M2, 32), 1, 1), 64, 0, stream>>>(
            x1, nm2, wt2, nullptr, x2, M2);
    // L3: 32 -> 64, KPER=27
    conv_direct<32, 64, 1, true>
        <<<dim3(cdiv(M3, 32), 2, 1), 64, 0, stream>>>(
            x2, nm3, wt3, nullptr, x3, M3);
    // L4: 64 -> 128, K-split 2 (KPER=27)
    conv_direct<64, 128, 2, false>
        <<<dim3(cdiv(M4, 32), 4, 2), 64, 0, stream>>>(
            x3, nm4, wt4, p4, nullptr, M4);
    reduce_bf<128><<<cdiv(M4 * 128, 256), 256, 0, stream>>>(p4, x4, M4 * 128, 2);
    // L5: 128 -> 512, K-split 4 (KPER=27)
    conv_direct<128, 512, 4, false>
        <<<dim3(cdiv(M5, 32), 16, 4), 64, 0, stream>>>(
            x4, nm5, wt5, p5, nullptr, M5);
    reduce_f32<<<cdiv(M5 * 512 / 4, 256), 256, 0, stream>>>(p5, (float*)d_out, M5 * 512 / 4, 4);
}